// Round 1
// baseline (11227.316 us; speedup 1.0000x reference)
//
#include <hip/hip_runtime.h>
#include <cstdint>
#include <cstddef>

#define DF 128
#define NLAYERS 5
#define BN_EPS 1e-5f

// HW fp32 atomic add (global_atomic_add_f32), no CAS loop.
__device__ __forceinline__ void atomAddF(float* p, float v) {
  unsafeAtomicAdd(p, v);
}

// ---------------- precompute kernels ----------------

__global__ void k_count_deg(const int* __restrict__ row, int* __restrict__ degi, int E) {
  int i = blockIdx.x * blockDim.x + threadIdx.x;
  if (i < E) atomicAdd(&degi[row[i]], 1);
}

__global__ void k_dinv(const int* __restrict__ degi, float* __restrict__ dinv, int N) {
  int i = blockIdx.x * blockDim.x + threadIdx.x;
  if (i < N) dinv[i] = 1.0f / sqrtf((float)(degi[i] + 1));
}

__global__ void k_norm(const int* __restrict__ row, const int* __restrict__ col,
                       const float* __restrict__ dinv, float* __restrict__ nrm, int E) {
  int i = blockIdx.x * blockDim.x + threadIdx.x;
  if (i < E) nrm[i] = dinv[row[i]] * dinv[col[i]];
}

// Pack edge_attr (int32 in [0,4)) -> 2 bits each; one uint16 per 8 features.
__global__ void k_pack(const int* __restrict__ ea, uint16_t* __restrict__ ep, int total) {
  int i = blockIdx.x * blockDim.x + threadIdx.x;
  if (i >= total) return;
  const int4* p = ((const int4*)ea) + (size_t)i * 2;
  int4 a = p[0], b = p[1];
  uint32_t v = (uint32_t)(a.x & 3)        | ((uint32_t)(a.y & 3) << 2) |
               ((uint32_t)(a.z & 3) << 4) | ((uint32_t)(a.w & 3) << 6) |
               ((uint32_t)(b.x & 3) << 8) | ((uint32_t)(b.y & 3) << 10) |
               ((uint32_t)(b.z & 3) << 12)| ((uint32_t)(b.w & 3) << 14);
  ep[i] = (uint16_t)v;
}

// BN eval-mode folded to affine: s = gamma/sqrt(var+eps), t = beta - mean*s
__global__ void k_bnprep(const float* __restrict__ g, const float* __restrict__ be,
                         const float* __restrict__ mn, const float* __restrict__ vr,
                         float* __restrict__ s, float* __restrict__ t, int n) {
  int i = blockIdx.x * blockDim.x + threadIdx.x;
  if (i < n) {
    float sc = g[i] / sqrtf(vr[i] + BN_EPS);
    s[i] = sc;
    t[i] = be[i] - mn[i] * sc;
  }
}

// ---------------- per-layer GEMM: hl = relu?(in) @ W^T + b ----------------
// Also writes accOut = s * ( relu(hl + root) / deg ) + t   (BN-folded self term,
// which seeds the scatter-add accumulator).
// Tile: 128 rows x 128 cols per block of 256 threads; 8x8 register blocking.
// A and W staged in LDS (64 KiB each) with XOR swizzle: unit = (row<<5)|(k4 ^ (row>>3)).
__global__ __launch_bounds__(256) void k_gemm(
    const float* __restrict__ in, const float* __restrict__ Wl,
    const float* __restrict__ bl, const float* __restrict__ rootl,
    const float* __restrict__ sl, const float* __restrict__ tl,
    const float* __restrict__ dinv,
    float* __restrict__ hl, float* __restrict__ accOut,
    int N, int applyRelu)
{
  __shared__ float4 Al[128 * 32];
  __shared__ float4 Wlds[128 * 32];
  const int t = threadIdx.x;
  const int row0 = blockIdx.x * 128;

  // stage W (coalesced read; swizzled conflict-free LDS write)
  #pragma unroll
  for (int rep = 0; rep < 16; ++rep) {
    int lin = rep * 256 + t;
    int r = lin >> 5, k4 = lin & 31;
    float4 w = ((const float4*)Wl)[lin];
    Wlds[(r << 5) | (k4 ^ (r >> 3))] = w;
  }
  // stage A (apply inter-layer ReLU on load; zero-pad tail rows)
  #pragma unroll
  for (int rep = 0; rep < 16; ++rep) {
    int lin = rep * 256 + t;
    int r = lin >> 5, k4 = lin & 31;
    int gn = row0 + r;
    float4 a = make_float4(0.f, 0.f, 0.f, 0.f);
    if (gn < N) {
      a = ((const float4*)in)[(size_t)gn * 32 + k4];
      if (applyRelu) {
        a.x = fmaxf(a.x, 0.f); a.y = fmaxf(a.y, 0.f);
        a.z = fmaxf(a.z, 0.f); a.w = fmaxf(a.w, 0.f);
      }
    }
    Al[(r << 5) | (k4 ^ (r >> 3))] = a;
  }
  __syncthreads();

  const int tx = t & 15;   // col group: cols tx*8 .. tx*8+7
  const int ty = t >> 4;   // row group: rows ty*8 .. ty*8+7

  float acc[8][8];
  #pragma unroll
  for (int i = 0; i < 8; ++i)
    #pragma unroll
    for (int j = 0; j < 8; ++j) acc[i][j] = 0.f;

  #pragma unroll 2
  for (int k4 = 0; k4 < 32; ++k4) {
    float4 av[8], wv[8];
    #pragma unroll
    for (int i = 0; i < 8; ++i) {
      int r = ty * 8 + i;                 // r>>3 == ty
      av[i] = Al[(r << 5) | (k4 ^ ty)];
    }
    #pragma unroll
    for (int j = 0; j < 8; ++j) {
      int c = tx * 8 + j;                 // c>>3 == tx
      wv[j] = Wlds[(c << 5) | (k4 ^ tx)];
    }
    #pragma unroll
    for (int i = 0; i < 8; ++i) {
      #pragma unroll
      for (int j = 0; j < 8; ++j) {
        acc[i][j] += av[i].x * wv[j].x;
        acc[i][j] += av[i].y * wv[j].y;
        acc[i][j] += av[i].z * wv[j].z;
        acc[i][j] += av[i].w * wv[j].w;
      }
    }
  }

  // per-column params for this thread's 8 columns
  float bb[8], rr[8], ss[8], tt[8];
  {
    const float4* p4;
    p4 = (const float4*)bl;    ((float4*)bb)[0] = p4[tx * 2]; ((float4*)bb)[1] = p4[tx * 2 + 1];
    p4 = (const float4*)rootl; ((float4*)rr)[0] = p4[tx * 2]; ((float4*)rr)[1] = p4[tx * 2 + 1];
    p4 = (const float4*)sl;    ((float4*)ss)[0] = p4[tx * 2]; ((float4*)ss)[1] = p4[tx * 2 + 1];
    p4 = (const float4*)tl;    ((float4*)tt)[0] = p4[tx * 2]; ((float4*)tt)[1] = p4[tx * 2 + 1];
  }

  #pragma unroll
  for (int i = 0; i < 8; ++i) {
    int gn = row0 + ty * 8 + i;
    if (gn >= N) continue;
    float di = dinv[gn];
    float invdeg = di * di;             // 1/deg
    float o[8], av2[8];
    #pragma unroll
    for (int j = 0; j < 8; ++j) {
      o[j] = acc[i][j] + bb[j];
      float se = fmaxf(o[j] + rr[j], 0.f) * invdeg;
      av2[j] = ss[j] * se + tt[j];
    }
    float* hp = hl + (size_t)gn * DF + tx * 8;
    ((float4*)hp)[0] = ((const float4*)o)[0];
    ((float4*)hp)[1] = ((const float4*)o)[1];
    float* ap = accOut + (size_t)gn * DF + tx * 8;
    ((float4*)ap)[0] = ((const float4*)av2)[0];
    ((float4*)ap)[1] = ((const float4*)av2)[1];
  }
}

// ---------------- per-layer edge kernel ----------------
// 16 threads per edge, 8 features each:
//   acc[col] += s * norm * relu(hl[row] + e)
__global__ __launch_bounds__(256) void k_edge(
    const int* __restrict__ row, const int* __restrict__ col,
    const float* __restrict__ nrm, const uint16_t* __restrict__ ep,
    const float* __restrict__ hl, const float* __restrict__ sl,
    float* __restrict__ acc, int E)
{
  int tid = blockIdx.x * blockDim.x + threadIdx.x;
  int e = tid >> 4, q = tid & 15;
  if (e >= E) return;
  int r = row[e], c = col[e];
  float nr = nrm[e];
  uint32_t p = ep[((size_t)e << 4) | q];
  const float4* h4 = (const float4*)(hl + ((size_t)r << 7) + (q << 3));
  float4 h0 = h4[0], h1 = h4[1];
  const float4* s4 = (const float4*)(sl + (q << 3));
  float4 s0 = s4[0], s1 = s4[1];
  float* dst = acc + ((size_t)c << 7) + (q << 3);
  float m;
  m = fmaxf(h0.x + (float)( p        & 3u), 0.f); atomAddF(dst + 0, s0.x * nr * m);
  m = fmaxf(h0.y + (float)((p >> 2)  & 3u), 0.f); atomAddF(dst + 1, s0.y * nr * m);
  m = fmaxf(h0.z + (float)((p >> 4)  & 3u), 0.f); atomAddF(dst + 2, s0.z * nr * m);
  m = fmaxf(h0.w + (float)((p >> 6)  & 3u), 0.f); atomAddF(dst + 3, s0.w * nr * m);
  m = fmaxf(h1.x + (float)((p >> 8)  & 3u), 0.f); atomAddF(dst + 4, s1.x * nr * m);
  m = fmaxf(h1.y + (float)((p >> 10) & 3u), 0.f); atomAddF(dst + 5, s1.y * nr * m);
  m = fmaxf(h1.z + (float)((p >> 12) & 3u), 0.f); atomAddF(dst + 6, s1.z * nr * m);
  m = fmaxf(h1.w + (float)((p >> 14) & 3u), 0.f); atomAddF(dst + 7, s1.w * nr * m);
}

// ---------------- launch ----------------
extern "C" void kernel_launch(void* const* d_in, const int* in_sizes, int n_in,
                              void* d_out, int out_size, void* d_ws, size_t ws_size,
                              hipStream_t stream) {
  const float* x     = (const float*)d_in[0];
  const int*   ei    = (const int*)d_in[1];
  const int*   ea    = (const int*)d_in[2];
  const float* W     = (const float*)d_in[3];
  const float* b     = (const float*)d_in[4];
  const float* root  = (const float*)d_in[5];
  const float* gamma = (const float*)d_in[6];
  const float* beta  = (const float*)d_in[7];
  const float* mean  = (const float*)d_in[8];
  const float* var   = (const float*)d_in[9];

  const int N = in_sizes[0] / DF;
  const int E = in_sizes[1] / 2;
  const int* row = ei;
  const int* col = ei + E;

  char* ws = (char*)d_ws;
  size_t off = 0;
  auto alloc = [&](size_t bytes) -> void* {
    void* p = ws + off;
    off = (off + bytes + 255) & ~(size_t)255;
    return p;
  };
  int*      degi = (int*)alloc((size_t)N * 4);
  float*    dinv = (float*)alloc((size_t)N * 4);
  float*    nrm  = (float*)alloc((size_t)E * 4);
  uint16_t* ep   = (uint16_t*)alloc((size_t)E * 16 * 2);
  float*    sbuf = (float*)alloc((size_t)NLAYERS * DF * 4);
  float*    tbuf = (float*)alloc((size_t)NLAYERS * DF * 4);
  float*    hl   = (float*)alloc((size_t)N * DF * 4);
  float*    accA = (float*)alloc((size_t)N * DF * 4);
  float*    accB = (float*)alloc((size_t)N * DF * 4);

  hipMemsetAsync(degi, 0, (size_t)N * 4, stream);
  k_count_deg<<<(E + 255) / 256, 256, 0, stream>>>(row, degi, E);
  k_dinv<<<(N + 255) / 256, 256, 0, stream>>>(degi, dinv, N);
  k_norm<<<(E + 255) / 256, 256, 0, stream>>>(row, col, dinv, nrm, E);
  k_pack<<<(E * 16 + 255) / 256, 256, 0, stream>>>(ea, ep, E * 16);
  k_bnprep<<<(NLAYERS * DF + 255) / 256, 256, 0, stream>>>(gamma, beta, mean, var,
                                                           sbuf, tbuf, NLAYERS * DF);

  const float* cur = x;
  float* outp = (float*)d_out;
  for (int l = 0; l < NLAYERS; ++l) {
    float* accOut = (l == NLAYERS - 1) ? outp : ((l & 1) ? accB : accA);
    k_gemm<<<(N + 127) / 128, 256, 0, stream>>>(
        cur, W + (size_t)l * DF * DF, b + (size_t)l * DF, root + (size_t)l * DF,
        sbuf + (size_t)l * DF, tbuf + (size_t)l * DF, dinv, hl, accOut, N, l > 0);
    k_edge<<<(E * 16 + 255) / 256, 256, 0, stream>>>(
        row, col, nrm, ep, hl, sbuf + (size_t)l * DF, accOut, E);
    cur = accOut;
  }
}

// Round 2
// 1059.676 us; speedup vs baseline: 10.5950x; 10.5950x over previous
//
#include <hip/hip_runtime.h>
#include <cstdint>
#include <cstddef>

#define DF 128
#define NL 5
#define BN_EPS 1e-5f

// ---------------- precompute kernels ----------------

// degi[row]++ (for deg used by dinv / self term), indeg[col]++ (CSR bucket sizes)
__global__ void k_deg2(const int* __restrict__ row, const int* __restrict__ col,
                       int* __restrict__ degi, int* __restrict__ indeg, int E) {
  int i = blockIdx.x * blockDim.x + threadIdx.x;
  if (i < E) {
    atomicAdd(&degi[row[i]], 1);
    atomicAdd(&indeg[col[i]], 1);
  }
}

__global__ void k_dinv(const int* __restrict__ degi, float* __restrict__ dinv, int N) {
  int i = blockIdx.x * blockDim.x + threadIdx.x;
  if (i < N) dinv[i] = 1.0f / sqrtf((float)(degi[i] + 1));
}

// disjoint contiguous bucket ranges via one global counter (order irrelevant)
__global__ void k_start(const int* __restrict__ indeg, int* __restrict__ start,
                        int* __restrict__ cursor, int* __restrict__ counter, int N) {
  int i = blockIdx.x * blockDim.x + threadIdx.x;
  if (i < N) {
    int s = atomicAdd(counter, indeg[i]);
    start[i] = s;
    cursor[i] = s;
  }
}

// scatter edges into destination buckets; record position for attr packing
__global__ void k_fill(const int* __restrict__ row, const int* __restrict__ col,
                       const float* __restrict__ dinv, int* __restrict__ cursor,
                       int* __restrict__ srcS, float* __restrict__ nrmS,
                       int* __restrict__ posOf, int E) {
  int e = blockIdx.x * blockDim.x + threadIdx.x;
  if (e >= E) return;
  int r = row[e], c = col[e];
  int pos = atomicAdd(&cursor[c], 1);
  srcS[pos] = r;
  nrmS[pos] = dinv[r] * dinv[c];
  posOf[e] = pos;
}

// pack edge_attr (int in [0,4)) -> 2 bits each, into destination-sorted order.
// 8 threads/edge, each packs 16 ints -> one uint32.
__global__ void k_packsort(const int* __restrict__ ea, const int* __restrict__ posOf,
                           uint32_t* __restrict__ epS, int E) {
  int tid = blockIdx.x * blockDim.x + threadIdx.x;
  int e = tid >> 3, t = tid & 7;
  if (e >= E) return;
  const int4* p = ((const int4*)ea) + (size_t)e * 32 + t * 4;
  uint32_t w = 0;
  #pragma unroll
  for (int q = 0; q < 4; ++q) {
    int4 a = p[q];
    w |= ((uint32_t)(a.x & 3)) << (8 * q);
    w |= ((uint32_t)(a.y & 3)) << (8 * q + 2);
    w |= ((uint32_t)(a.z & 3)) << (8 * q + 4);
    w |= ((uint32_t)(a.w & 3)) << (8 * q + 6);
  }
  epS[(size_t)posOf[e] * 8 + t] = w;
}

// BN eval-mode folded to affine: s = gamma/sqrt(var+eps), t = beta - mean*s
__global__ void k_bnprep(const float* __restrict__ g, const float* __restrict__ be,
                         const float* __restrict__ mn, const float* __restrict__ vr,
                         float* __restrict__ s, float* __restrict__ t, int n) {
  int i = blockIdx.x * blockDim.x + threadIdx.x;
  if (i < n) {
    float sc = g[i] / sqrtf(vr[i] + BN_EPS);
    s[i] = sc;
    t[i] = be[i] - mn[i] * sc;
  }
}

// ---------------- per-layer GEMM: hl = relu?(in) @ W^T + b ----------------
// Also seeds accOut = s * ( relu(hl + root) / deg ) + t  (BN-folded self term).
// NOTE: `in` may alias `accOut` (in-place layers) — row-block-local, reads
// staged to LDS before writes, so no __restrict__ on these two.
__global__ __launch_bounds__(256) void k_gemm(
    const float* in, const float* __restrict__ Wl,
    const float* __restrict__ bl, const float* __restrict__ rootl,
    const float* __restrict__ sl, const float* __restrict__ tl,
    const float* __restrict__ dinv,
    float* __restrict__ hl, float* accOut,
    int N, int applyRelu)
{
  __shared__ float4 Al[128 * 32];
  __shared__ float4 Wlds[128 * 32];
  const int t = threadIdx.x;
  const int row0 = blockIdx.x * 128;

  #pragma unroll
  for (int rep = 0; rep < 16; ++rep) {
    int lin = rep * 256 + t;
    int r = lin >> 5, k4 = lin & 31;
    float4 w = ((const float4*)Wl)[lin];
    Wlds[(r << 5) | (k4 ^ (r >> 3))] = w;
  }
  #pragma unroll
  for (int rep = 0; rep < 16; ++rep) {
    int lin = rep * 256 + t;
    int r = lin >> 5, k4 = lin & 31;
    int gn = row0 + r;
    float4 a = make_float4(0.f, 0.f, 0.f, 0.f);
    if (gn < N) {
      a = ((const float4*)in)[(size_t)gn * 32 + k4];
      if (applyRelu) {
        a.x = fmaxf(a.x, 0.f); a.y = fmaxf(a.y, 0.f);
        a.z = fmaxf(a.z, 0.f); a.w = fmaxf(a.w, 0.f);
      }
    }
    Al[(r << 5) | (k4 ^ (r >> 3))] = a;
  }
  __syncthreads();

  const int tx = t & 15;
  const int ty = t >> 4;

  float acc[8][8];
  #pragma unroll
  for (int i = 0; i < 8; ++i)
    #pragma unroll
    for (int j = 0; j < 8; ++j) acc[i][j] = 0.f;

  #pragma unroll 2
  for (int k4 = 0; k4 < 32; ++k4) {
    float4 av[8], wv[8];
    #pragma unroll
    for (int i = 0; i < 8; ++i) {
      int r = ty * 8 + i;
      av[i] = Al[(r << 5) | (k4 ^ ty)];
    }
    #pragma unroll
    for (int j = 0; j < 8; ++j) {
      int c = tx * 8 + j;
      wv[j] = Wlds[(c << 5) | (k4 ^ tx)];
    }
    #pragma unroll
    for (int i = 0; i < 8; ++i) {
      #pragma unroll
      for (int j = 0; j < 8; ++j) {
        acc[i][j] += av[i].x * wv[j].x;
        acc[i][j] += av[i].y * wv[j].y;
        acc[i][j] += av[i].z * wv[j].z;
        acc[i][j] += av[i].w * wv[j].w;
      }
    }
  }

  float bb[8], rr[8], ss[8], tt[8];
  {
    const float4* p4;
    p4 = (const float4*)bl;    ((float4*)bb)[0] = p4[tx * 2]; ((float4*)bb)[1] = p4[tx * 2 + 1];
    p4 = (const float4*)rootl; ((float4*)rr)[0] = p4[tx * 2]; ((float4*)rr)[1] = p4[tx * 2 + 1];
    p4 = (const float4*)sl;    ((float4*)ss)[0] = p4[tx * 2]; ((float4*)ss)[1] = p4[tx * 2 + 1];
    p4 = (const float4*)tl;    ((float4*)tt)[0] = p4[tx * 2]; ((float4*)tt)[1] = p4[tx * 2 + 1];
  }

  #pragma unroll
  for (int i = 0; i < 8; ++i) {
    int gn = row0 + ty * 8 + i;
    if (gn >= N) continue;
    float di = dinv[gn];
    float invdeg = di * di;
    float o[8], av2[8];
    #pragma unroll
    for (int j = 0; j < 8; ++j) {
      o[j] = acc[i][j] + bb[j];
      float se = fmaxf(o[j] + rr[j], 0.f) * invdeg;
      av2[j] = ss[j] * se + tt[j];
    }
    float* hp = hl + (size_t)gn * DF + tx * 8;
    ((float4*)hp)[0] = ((const float4*)o)[0];
    ((float4*)hp)[1] = ((const float4*)o)[1];
    float* ap = accOut + (size_t)gn * DF + tx * 8;
    ((float4*)ap)[0] = ((const float4*)av2)[0];
    ((float4*)ap)[1] = ((const float4*)av2)[1];
  }
}

// ---------------- per-layer segmented gather-reduce ----------------
// One wave per destination node; 2 features per lane.
//   acc[i] = seed[i] + s * sum_{e in bucket(i)} nrm[e] * relu(hl[src[e]] + attr[e])
__global__ __launch_bounds__(256) void k_gather(
    const int* __restrict__ start, const int* __restrict__ indeg,
    const int* __restrict__ srcS, const float* __restrict__ nrmS,
    const uint32_t* __restrict__ epS,
    const float* __restrict__ hl, const float* __restrict__ sl,
    float* acc, int N)
{
  int wid = (blockIdx.x * blockDim.x + threadIdx.x) >> 6;
  int lane = threadIdx.x & 63;
  if (wid >= N) return;
  int base = start[wid];
  int n = indeg[wid];
  const uint32_t sh = (lane & 7) * 4;
  const int dw = lane >> 3;
  const float2* h2 = (const float2*)hl;
  float a0 = 0.f, a1 = 0.f;
  #pragma unroll 2
  for (int k = 0; k < n; ++k) {
    int idx = base + k;
    int src = srcS[idx];
    float nr = nrmS[idx];
    uint32_t pw = epS[(size_t)idx * 8 + dw];
    float2 h = h2[(size_t)src * 64 + lane];
    float e0 = (float)((pw >> sh) & 3u);
    float e1 = (float)((pw >> (sh + 2)) & 3u);
    a0 += nr * fmaxf(h.x + e0, 0.f);
    a1 += nr * fmaxf(h.y + e1, 0.f);
  }
  float2 sv = ((const float2*)sl)[lane];
  float2* o2 = (float2*)acc + (size_t)wid * 64 + lane;
  float2 o = *o2;
  o.x += sv.x * a0;
  o.y += sv.y * a1;
  *o2 = o;
}

// ---------------- launch ----------------
extern "C" void kernel_launch(void* const* d_in, const int* in_sizes, int n_in,
                              void* d_out, int out_size, void* d_ws, size_t ws_size,
                              hipStream_t stream) {
  const float* x     = (const float*)d_in[0];
  const int*   ei    = (const int*)d_in[1];
  const int*   ea    = (const int*)d_in[2];
  const float* W     = (const float*)d_in[3];
  const float* b     = (const float*)d_in[4];
  const float* root  = (const float*)d_in[5];
  const float* gamma = (const float*)d_in[6];
  const float* beta  = (const float*)d_in[7];
  const float* mean  = (const float*)d_in[8];
  const float* var   = (const float*)d_in[9];

  const int N = in_sizes[0] / DF;
  const int E = in_sizes[1] / 2;
  const int* row = ei;
  const int* col = ei + E;

  char* ws = (char*)d_ws;
  size_t off = 0;
  auto alloc = [&](size_t bytes) -> void* {
    void* p = ws + off;
    off = (off + bytes + 255) & ~(size_t)255;
    return p;
  };
  int*      degi   = (int*)alloc((size_t)N * 4);
  int*      indeg  = (int*)alloc((size_t)N * 4);
  int*      counter= (int*)alloc(256);
  float*    dinv   = (float*)alloc((size_t)N * 4);
  int*      startA = (int*)alloc((size_t)N * 4);
  int*      cursor = (int*)alloc((size_t)N * 4);
  int*      srcS   = (int*)alloc((size_t)E * 4);
  float*    nrmS   = (float*)alloc((size_t)E * 4);
  int*      posOf  = (int*)alloc((size_t)E * 4);
  uint32_t* epS    = (uint32_t*)alloc((size_t)E * 8 * 4);
  float*    sbuf   = (float*)alloc((size_t)NL * DF * 4);
  float*    tbuf   = (float*)alloc((size_t)NL * DF * 4);
  float*    hl     = (float*)alloc((size_t)N * DF * 4);
  float*    accA   = (float*)alloc((size_t)N * DF * 4);

  hipMemsetAsync(degi, 0, (size_t)N * 4, stream);
  hipMemsetAsync(indeg, 0, (size_t)N * 4, stream);
  hipMemsetAsync(counter, 0, 256, stream);

  k_deg2<<<(E + 255) / 256, 256, 0, stream>>>(row, col, degi, indeg, E);
  k_dinv<<<(N + 255) / 256, 256, 0, stream>>>(degi, dinv, N);
  k_start<<<(N + 255) / 256, 256, 0, stream>>>(indeg, startA, cursor, counter, N);
  k_fill<<<(E + 255) / 256, 256, 0, stream>>>(row, col, dinv, cursor, srcS, nrmS, posOf, E);
  k_packsort<<<(E * 8 + 255) / 256, 256, 0, stream>>>(ea, posOf, epS, E);
  k_bnprep<<<(NL * DF + 255) / 256, 256, 0, stream>>>(gamma, beta, mean, var,
                                                      sbuf, tbuf, NL * DF);

  float* outp = (float*)d_out;
  const float* cur = x;
  for (int l = 0; l < NL; ++l) {
    float* accOut = (l == NL - 1) ? outp : accA;   // layers 1..3 run in-place on accA
    k_gemm<<<(N + 127) / 128, 256, 0, stream>>>(
        cur, W + (size_t)l * DF * DF, b + (size_t)l * DF, root + (size_t)l * DF,
        sbuf + (size_t)l * DF, tbuf + (size_t)l * DF, dinv, hl, accOut, N, l > 0);
    k_gather<<<((N + 3) / 4), 256, 0, stream>>>(
        startA, indeg, srcS, nrmS, epS, hl, sbuf + (size_t)l * DF, accOut, N);
    cur = accOut;
  }
}

// Round 3
// 613.158 us; speedup vs baseline: 18.3106x; 1.7282x over previous
//
#include <hip/hip_runtime.h>
#include <cstdint>
#include <cstddef>

#define DF 128
#define NL 5
#define BN_EPS 1e-5f

typedef short bf16x8 __attribute__((ext_vector_type(8)));
typedef float f32x4 __attribute__((ext_vector_type(4)));

// fp32 -> bf16 (RNE)
__device__ __forceinline__ ushort f2b(float f) {
  union { float f; uint32_t u; } v; v.f = f;
  uint32_t u = v.u + 0x7fffu + ((v.u >> 16) & 1u);
  return (ushort)(u >> 16);
}
__device__ __forceinline__ float b2f(uint32_t lo16) {
  union { uint32_t u; float f; } v; v.u = lo16 << 16;
  return v.f;
}
__device__ __forceinline__ uint32_t pk2(float a, float b) {
  return (uint32_t)f2b(a) | ((uint32_t)f2b(b) << 16);
}
// relu on 2 packed bf16
__device__ __forceinline__ uint32_t relu2(uint32_t p) {
  uint32_t mlo = ((p >> 15) & 1u) * 0x0000ffffu;
  uint32_t mhi = (p >> 31) * 0xffff0000u;
  return p & ~(mlo | mhi);
}

// ---------------- precompute kernels ----------------

__global__ void k_deg2(const int* __restrict__ row, const int* __restrict__ col,
                       int* __restrict__ degi, int* __restrict__ indeg, int E) {
  int i = blockIdx.x * blockDim.x + threadIdx.x;
  if (i < E) {
    atomicAdd(&degi[row[i]], 1);
    atomicAdd(&indeg[col[i]], 1);
  }
}

__global__ void k_dinv(const int* __restrict__ degi, float* __restrict__ dinv, int N) {
  int i = blockIdx.x * blockDim.x + threadIdx.x;
  if (i < N) dinv[i] = 1.0f / sqrtf((float)(degi[i] + 1));
}

__global__ void k_start(const int* __restrict__ indeg, int* __restrict__ start,
                        int* __restrict__ cursor, int* __restrict__ counter, int N) {
  int i = blockIdx.x * blockDim.x + threadIdx.x;
  if (i < N) {
    int s = atomicAdd(counter, indeg[i]);
    start[i] = s;
    cursor[i] = s;
  }
}

__global__ void k_fill(const int* __restrict__ row, const int* __restrict__ col,
                       const float* __restrict__ dinv, int* __restrict__ cursor,
                       int* __restrict__ srcS, float* __restrict__ nrmS,
                       int* __restrict__ posOf, int E) {
  int e = blockIdx.x * blockDim.x + threadIdx.x;
  if (e >= E) return;
  int r = row[e], c = col[e];
  int pos = atomicAdd(&cursor[c], 1);
  srcS[pos] = r;
  nrmS[pos] = dinv[r] * dinv[c];
  posOf[e] = pos;
}

__global__ void k_packsort(const int* __restrict__ ea, const int* __restrict__ posOf,
                           uint32_t* __restrict__ epS, int E) {
  int tid = blockIdx.x * blockDim.x + threadIdx.x;
  int e = tid >> 3, t = tid & 7;
  if (e >= E) return;
  const int4* p = ((const int4*)ea) + (size_t)e * 32 + t * 4;
  uint32_t w = 0;
  #pragma unroll
  for (int q = 0; q < 4; ++q) {
    int4 a = p[q];
    w |= ((uint32_t)(a.x & 3)) << (8 * q);
    w |= ((uint32_t)(a.y & 3)) << (8 * q + 2);
    w |= ((uint32_t)(a.z & 3)) << (8 * q + 4);
    w |= ((uint32_t)(a.w & 3)) << (8 * q + 6);
  }
  epS[(size_t)posOf[e] * 8 + t] = w;
}

__global__ void k_bnprep(const float* __restrict__ g, const float* __restrict__ be,
                         const float* __restrict__ mn, const float* __restrict__ vr,
                         float* __restrict__ s, float* __restrict__ t, int n) {
  int i = blockIdx.x * blockDim.x + threadIdx.x;
  if (i < n) {
    float sc = g[i] / sqrtf(vr[i] + BN_EPS);
    s[i] = sc;
    t[i] = be[i] - mn[i] * sc;
  }
}

__global__ void k_wconv(const float* __restrict__ W, ushort* __restrict__ Wb, int total) {
  int i = blockIdx.x * blockDim.x + threadIdx.x;
  if (i < total) Wb[i] = f2b(W[i]);
}

// ---------------- MFMA GEMM: hl = relu?(in) @ W^T + b ----------------
// in: fp32 (layer 0) or bf16; accOut seeded with BN-folded self term,
// bf16 (layers 0..3) or fp32 (last layer -> d_out). `in` may alias accOut
// (in-place): reads are row-block-local and staged before any writes.
// LDS: [128 rows][16 units of 16B] bf16, swizzle unit^= (row&7).
template <typename IT, typename AT>
__global__ __launch_bounds__(256) void k_gemm(
    const IT* in, const ushort* __restrict__ Wb,
    const float* __restrict__ bl, const float* __restrict__ rootl,
    const float* __restrict__ sl, const float* __restrict__ tl,
    const float* __restrict__ dinv,
    ushort* __restrict__ hl, AT* accOut,
    int N, int applyRelu)
{
  __shared__ uint4 lA[128 * 16];
  __shared__ uint4 lW[128 * 16];
  const int t = threadIdx.x;
  const int row0 = blockIdx.x * 128;

  // stage W (bf16, direct)
  #pragma unroll
  for (int it = 0; it < 8; ++it) {
    int lin = it * 256 + t;
    int r = lin >> 4, u = lin & 15;
    lW[(r << 4) | (u ^ (r & 7))] = ((const uint4*)Wb)[lin];
  }
  // stage A (convert if fp32; relu if requested)
  #pragma unroll
  for (int it = 0; it < 8; ++it) {
    int lin = it * 256 + t;
    int r = lin >> 4, u = lin & 15;
    int gn = row0 + r;
    uint4 pk = make_uint4(0u, 0u, 0u, 0u);
    if (gn < N) {
      if constexpr (sizeof(IT) == 4) {
        const float4* p = (const float4*)((const float*)in + (size_t)gn * DF + u * 8);
        float4 f0 = p[0], f1 = p[1];
        if (applyRelu) {
          f0.x = fmaxf(f0.x, 0.f); f0.y = fmaxf(f0.y, 0.f);
          f0.z = fmaxf(f0.z, 0.f); f0.w = fmaxf(f0.w, 0.f);
          f1.x = fmaxf(f1.x, 0.f); f1.y = fmaxf(f1.y, 0.f);
          f1.z = fmaxf(f1.z, 0.f); f1.w = fmaxf(f1.w, 0.f);
        }
        pk.x = pk2(f0.x, f0.y); pk.y = pk2(f0.z, f0.w);
        pk.z = pk2(f1.x, f1.y); pk.w = pk2(f1.z, f1.w);
      } else {
        pk = ((const uint4*)in)[(size_t)gn * 16 + u];
        if (applyRelu) {
          pk.x = relu2(pk.x); pk.y = relu2(pk.y);
          pk.z = relu2(pk.z); pk.w = relu2(pk.w);
        }
      }
    }
    lA[(r << 4) | (u ^ (r & 7))] = pk;
  }
  __syncthreads();

  const int wv = t >> 6;        // wave 0..3 -> rows wv*32..wv*32+31
  const int l  = t & 63;
  const int lr = l & 15;        // row-in-frag (A) / col-in-frag (B, C/D)
  const int lk = l >> 4;        // k-group; C/D row group

  f32x4 acc[2][8];
  #pragma unroll
  for (int rt = 0; rt < 2; ++rt)
    #pragma unroll
    for (int ct = 0; ct < 8; ++ct) acc[rt][ct] = (f32x4){0.f, 0.f, 0.f, 0.f};

  #pragma unroll
  for (int ks = 0; ks < 4; ++ks) {
    const int kofs = ks * 4 + lk;
    bf16x8 af[2], wf[8];
    #pragma unroll
    for (int rt = 0; rt < 2; ++rt) {
      int r = wv * 32 + rt * 16 + lr;
      af[rt] = *reinterpret_cast<const bf16x8*>(&lA[(r << 4) | (kofs ^ (r & 7))]);
    }
    #pragma unroll
    for (int ct = 0; ct < 8; ++ct) {
      int r = ct * 16 + lr;
      wf[ct] = *reinterpret_cast<const bf16x8*>(&lW[(r << 4) | (kofs ^ (r & 7))]);
    }
    #pragma unroll
    for (int rt = 0; rt < 2; ++rt)
      #pragma unroll
      for (int ct = 0; ct < 8; ++ct)
        acc[rt][ct] = __builtin_amdgcn_mfma_f32_16x16x32_bf16(af[rt], wf[ct], acc[rt][ct], 0, 0, 0);
  }

  // per-column params (col = ct*16 + lr)
  float bb[8], rr[8], ss[8], tt[8];
  #pragma unroll
  for (int ct = 0; ct < 8; ++ct) {
    int c = ct * 16 + lr;
    bb[ct] = bl[c]; rr[ct] = rootl[c]; ss[ct] = sl[c]; tt[ct] = tl[c];
  }

  #pragma unroll
  for (int rt = 0; rt < 2; ++rt) {
    #pragma unroll
    for (int rg = 0; rg < 4; ++rg) {
      int gn = row0 + wv * 32 + rt * 16 + lk * 4 + rg;
      if (gn >= N) continue;
      float di = dinv[gn];
      float invdeg = di * di;
      #pragma unroll
      for (int ct = 0; ct < 8; ++ct) {
        int c = ct * 16 + lr;
        float o = acc[rt][ct][rg] + bb[ct];
        hl[(size_t)gn * DF + c] = f2b(o);
        float se = fmaxf(o + rr[ct], 0.f) * invdeg;
        float av2 = ss[ct] * se + tt[ct];
        if constexpr (sizeof(AT) == 4) accOut[(size_t)gn * DF + c] = av2;
        else                           accOut[(size_t)gn * DF + c] = f2b(av2);
      }
    }
  }
}

// ---------------- segmented gather-reduce ----------------
// One wave per destination node; 2 features/lane (bf16 hl).
template <typename AT>
__global__ __launch_bounds__(256) void k_gather(
    const int* __restrict__ start, const int* __restrict__ indeg,
    const int* __restrict__ srcS, const float* __restrict__ nrmS,
    const uint32_t* __restrict__ epS,
    const uint32_t* __restrict__ hl2,   // 2 bf16 per dword
    const float* __restrict__ sl,
    AT* acc, int N)
{
  int wid = (blockIdx.x * blockDim.x + threadIdx.x) >> 6;
  int lane = threadIdx.x & 63;
  if (wid >= N) return;
  int base = start[wid];
  int n = indeg[wid];
  const uint32_t sh = (lane & 7) * 4;
  const int dw = lane >> 3;
  float a0 = 0.f, a1 = 0.f;
  #pragma unroll 2
  for (int k = 0; k < n; ++k) {
    int idx = base + k;
    int src = srcS[idx];
    float nr = nrmS[idx];
    uint32_t pw = epS[(size_t)idx * 8 + dw];
    uint32_t hw = hl2[(size_t)src * 64 + lane];
    float h0 = b2f(hw & 0xffffu);
    float h1 = b2f(hw >> 16);
    float e0 = (float)((pw >> sh) & 3u);
    float e1 = (float)((pw >> (sh + 2)) & 3u);
    a0 += nr * fmaxf(h0 + e0, 0.f);
    a1 += nr * fmaxf(h1 + e1, 0.f);
  }
  float2 sv = ((const float2*)sl)[lane];
  if constexpr (sizeof(AT) == 4) {
    float2* o2 = (float2*)acc + (size_t)wid * 64 + lane;
    float2 o = *o2;
    o.x += sv.x * a0;
    o.y += sv.y * a1;
    *o2 = o;
  } else {
    uint32_t* o2 = (uint32_t*)acc + (size_t)wid * 64 + lane;
    uint32_t p = *o2;
    float o0 = b2f(p & 0xffffu) + sv.x * a0;
    float o1 = b2f(p >> 16) + sv.y * a1;
    *o2 = pk2(o0, o1);
  }
}

// ---------------- launch ----------------
extern "C" void kernel_launch(void* const* d_in, const int* in_sizes, int n_in,
                              void* d_out, int out_size, void* d_ws, size_t ws_size,
                              hipStream_t stream) {
  const float* x     = (const float*)d_in[0];
  const int*   ei    = (const int*)d_in[1];
  const int*   ea    = (const int*)d_in[2];
  const float* W     = (const float*)d_in[3];
  const float* b     = (const float*)d_in[4];
  const float* root  = (const float*)d_in[5];
  const float* gamma = (const float*)d_in[6];
  const float* beta  = (const float*)d_in[7];
  const float* mean  = (const float*)d_in[8];
  const float* var   = (const float*)d_in[9];

  const int N = in_sizes[0] / DF;
  const int E = in_sizes[1] / 2;
  const int* row = ei;
  const int* col = ei + E;

  char* ws = (char*)d_ws;
  size_t off = 0;
  auto alloc = [&](size_t bytes) -> void* {
    void* p = ws + off;
    off = (off + bytes + 255) & ~(size_t)255;
    return p;
  };
  int*      degi   = (int*)alloc((size_t)N * 4);
  int*      indeg  = (int*)alloc((size_t)N * 4);
  int*      counter= (int*)alloc(256);
  float*    dinv   = (float*)alloc((size_t)N * 4);
  int*      startA = (int*)alloc((size_t)N * 4);
  int*      cursor = (int*)alloc((size_t)N * 4);
  int*      srcS   = (int*)alloc((size_t)E * 4);
  float*    nrmS   = (float*)alloc((size_t)E * 4);
  int*      posOf  = (int*)alloc((size_t)E * 4);
  uint32_t* epS    = (uint32_t*)alloc((size_t)E * 8 * 4);
  float*    sbuf   = (float*)alloc((size_t)NL * DF * 4);
  float*    tbuf   = (float*)alloc((size_t)NL * DF * 4);
  ushort*   Wb     = (ushort*)alloc((size_t)NL * DF * DF * 2);
  ushort*   hl     = (ushort*)alloc((size_t)N * DF * 2);
  ushort*   accA   = (ushort*)alloc((size_t)N * DF * 2);

  hipMemsetAsync(degi, 0, (size_t)N * 4, stream);
  hipMemsetAsync(indeg, 0, (size_t)N * 4, stream);
  hipMemsetAsync(counter, 0, 256, stream);

  k_deg2<<<(E + 255) / 256, 256, 0, stream>>>(row, col, degi, indeg, E);
  k_dinv<<<(N + 255) / 256, 256, 0, stream>>>(degi, dinv, N);
  k_start<<<(N + 255) / 256, 256, 0, stream>>>(indeg, startA, cursor, counter, N);
  k_fill<<<(E + 255) / 256, 256, 0, stream>>>(row, col, dinv, cursor, srcS, nrmS, posOf, E);
  k_packsort<<<(E * 8 + 255) / 256, 256, 0, stream>>>(ea, posOf, epS, E);
  k_bnprep<<<(NL * DF + 255) / 256, 256, 0, stream>>>(gamma, beta, mean, var,
                                                      sbuf, tbuf, NL * DF);
  k_wconv<<<(NL * DF * DF + 255) / 256, 256, 0, stream>>>(W, Wb, NL * DF * DF);

  float* outp = (float*)d_out;
  const int gemmGrid = (N + 127) / 128;
  const int gathGrid = (N + 3) / 4;

  // layer 0: fp32 in -> bf16 acc
  k_gemm<float, ushort><<<gemmGrid, 256, 0, stream>>>(
      x, Wb, b, root, sbuf, tbuf, dinv, hl, accA, N, 0);
  k_gather<ushort><<<gathGrid, 256, 0, stream>>>(
      startA, indeg, srcS, nrmS, epS, (const uint32_t*)hl, sbuf, accA, N);

  // layers 1..3: bf16 in-place
  for (int l = 1; l < NL - 1; ++l) {
    k_gemm<ushort, ushort><<<gemmGrid, 256, 0, stream>>>(
        accA, Wb + (size_t)l * DF * DF, b + (size_t)l * DF, root + (size_t)l * DF,
        sbuf + (size_t)l * DF, tbuf + (size_t)l * DF, dinv, hl, accA, N, 1);
    k_gather<ushort><<<gathGrid, 256, 0, stream>>>(
        startA, indeg, srcS, nrmS, epS, (const uint32_t*)hl,
        sbuf + (size_t)l * DF, accA, N);
  }

  // layer 4: bf16 in -> fp32 out (d_out)
  {
    const int l = NL - 1;
    k_gemm<ushort, float><<<gemmGrid, 256, 0, stream>>>(
        accA, Wb + (size_t)l * DF * DF, b + (size_t)l * DF, root + (size_t)l * DF,
        sbuf + (size_t)l * DF, tbuf + (size_t)l * DF, dinv, hl, outp, N, 1);
    k_gather<float><<<gathGrid, 256, 0, stream>>>(
        startA, indeg, srcS, nrmS, epS, (const uint32_t*)hl,
        sbuf + (size_t)l * DF, outp, N);
  }
}

// Round 4
// 464.275 us; speedup vs baseline: 24.1824x; 1.3207x over previous
//
#include <hip/hip_runtime.h>
#include <cstdint>
#include <cstddef>

#define DF 128
#define NL 5
#define BN_EPS 1e-5f

typedef short bf16x8 __attribute__((ext_vector_type(8)));
typedef float f32x4 __attribute__((ext_vector_type(4)));

typedef __attribute__((address_space(3))) uint32_t lds_u32;
typedef __attribute__((address_space(1))) uint32_t glb_u32;

__device__ __forceinline__ void gload16(const void* g, void* l) {
#if __has_builtin(__builtin_amdgcn_global_load_lds)
  __builtin_amdgcn_global_load_lds((const glb_u32*)g, (lds_u32*)l, 16, 0, 0);
#else
  *(uint4*)l = *(const uint4*)g;   // fallback (never taken on gfx950)
#endif
}

// fp32 -> bf16 (RNE)
__device__ __forceinline__ ushort f2b(float f) {
  union { float f; uint32_t u; } v; v.f = f;
  uint32_t u = v.u + 0x7fffu + ((v.u >> 16) & 1u);
  return (ushort)(u >> 16);
}
__device__ __forceinline__ float b2f(uint32_t lo16) {
  union { uint32_t u; float f; } v; v.u = lo16 << 16;
  return v.f;
}
__device__ __forceinline__ uint32_t pk2(float a, float b) {
  return (uint32_t)f2b(a) | ((uint32_t)f2b(b) << 16);
}

// ---------------- precompute kernels ----------------

__global__ void k_deg2(const int* __restrict__ row, const int* __restrict__ col,
                       int* __restrict__ degi, int* __restrict__ indeg, int E) {
  int i = blockIdx.x * blockDim.x + threadIdx.x;
  if (i < E) {
    atomicAdd(&degi[row[i]], 1);
    atomicAdd(&indeg[col[i]], 1);
  }
}

__global__ void k_dinv(const int* __restrict__ degi, float* __restrict__ dinv, int N) {
  int i = blockIdx.x * blockDim.x + threadIdx.x;
  if (i < N) dinv[i] = 1.0f / sqrtf((float)(degi[i] + 1));
}

__global__ void k_start(const int* __restrict__ indeg, int* __restrict__ start,
                        int* __restrict__ cursor, int* __restrict__ counter, int N) {
  int i = blockIdx.x * blockDim.x + threadIdx.x;
  if (i < N) {
    int s = atomicAdd(counter, indeg[i]);
    start[i] = s;
    cursor[i] = s;
  }
}

// fused: bucket-scatter edge + pack its 128 attrs (2b each) into dst-sorted slot.
// 8 threads per edge; leader does the cursor atomic and src/nrm write.
__global__ void k_fillpack(const int* __restrict__ row, const int* __restrict__ col,
                           const float* __restrict__ dinv, int* __restrict__ cursor,
                           int* __restrict__ srcS, float* __restrict__ nrmS,
                           const int* __restrict__ ea, uint32_t* __restrict__ epS, int E) {
  int tid = blockIdx.x * blockDim.x + threadIdx.x;
  int e = tid >> 3, t = tid & 7;
  if (e >= E) return;
  int pos;
  if (t == 0) {
    int r = row[e], c = col[e];
    pos = atomicAdd(&cursor[c], 1);
    srcS[pos] = r;
    nrmS[pos] = dinv[r] * dinv[c];
  }
  pos = __shfl(pos, 0, 8);
  const int4* p = ((const int4*)ea) + (size_t)e * 32 + t * 4;
  uint32_t w = 0;
  #pragma unroll
  for (int q = 0; q < 4; ++q) {
    int4 a = p[q];
    w |= ((uint32_t)(a.x & 3)) << (8 * q);
    w |= ((uint32_t)(a.y & 3)) << (8 * q + 2);
    w |= ((uint32_t)(a.z & 3)) << (8 * q + 4);
    w |= ((uint32_t)(a.w & 3)) << (8 * q + 6);
  }
  epS[(size_t)pos * 8 + t] = w;
}

// fused: BN affine fold + W fp32->bf16 conversion
__global__ void k_params(const float* __restrict__ g, const float* __restrict__ be,
                         const float* __restrict__ mn, const float* __restrict__ vr,
                         float* __restrict__ s, float* __restrict__ t,
                         const float* __restrict__ W, ushort* __restrict__ Wb,
                         int nbn, int nw) {
  int i = blockIdx.x * blockDim.x + threadIdx.x;
  if (i < nw) Wb[i] = f2b(W[i]);
  if (i < nbn) {
    float sc = g[i] / sqrtf(vr[i] + BN_EPS);
    s[i] = sc;
    t[i] = be[i] - mn[i] * sc;
  }
}

// ---------------- MFMA GEMM: hl = in @ W^T + b ----------------
// (input relu already applied by previous gather's epilogue)
// Seeds accOut = s*(relu(hl+root)/deg)+t (BN-folded self term).
// `in` may alias accOut (in-place): reads complete at the barrier before any
// epilogue write; rows are block-local.
// LDS linear [r][u] holds global unit (r, u^(r&7)) -> fragment read XORs back.
template <typename IT, typename AT>
__global__ __launch_bounds__(256) void k_gemm(
    const IT* in, const ushort* __restrict__ Wb,
    const float* __restrict__ bl, const float* __restrict__ rootl,
    const float* __restrict__ sl, const float* __restrict__ tl,
    const float* __restrict__ dinv,
    ushort* __restrict__ hl, AT* accOut, int N)
{
  __shared__ uint4 lA[128 * 16];
  __shared__ uint4 lW[128 * 16];
  const int t = threadIdx.x;
  const int row0 = blockIdx.x * 128;
  const int wv = t >> 6;
  const int l  = t & 63;

  // stage W via global_load_lds (pre-swizzled source)
  #pragma unroll
  for (int it = 0; it < 8; ++it) {
    int ubase = (it * 4 + wv) * 64;          // wave-uniform LDS unit base
    int lin = ubase + l;
    int r = lin >> 4, u = lin & 15;
    gload16((const uint4*)Wb + (r << 4) + (u ^ (r & 7)), lA /*dummy*/ + 0 == nullptr ? nullptr : (void*)(lW + ubase));
  }

  if constexpr (sizeof(IT) == 2) {
    // stage A (bf16) via global_load_lds, pre-swizzled source, clamped tail
    #pragma unroll
    for (int it = 0; it < 8; ++it) {
      int ubase = (it * 4 + wv) * 64;
      int lin = ubase + l;
      int r = lin >> 4, u = lin & 15;
      int gn = row0 + r;
      int gnc = gn < N ? gn : N - 1;         // clamped: garbage rows are discarded
      gload16((const uint4*)in + (size_t)gnc * 16 + (u ^ (r & 7)), (void*)(lA + ubase));
    }
  } else {
    // layer 0: fp32 input, convert in registers
    #pragma unroll
    for (int it = 0; it < 8; ++it) {
      int lin = it * 256 + t;
      int r = lin >> 4, u = lin & 15;
      int gn = row0 + r;
      uint4 pk = make_uint4(0u, 0u, 0u, 0u);
      if (gn < N) {
        const float4* p = (const float4*)((const float*)in + (size_t)gn * DF + u * 8);
        float4 f0 = p[0], f1 = p[1];
        pk.x = pk2(f0.x, f0.y); pk.y = pk2(f0.z, f0.w);
        pk.z = pk2(f1.x, f1.y); pk.w = pk2(f1.z, f1.w);
      }
      lA[(r << 4) | (u ^ (r & 7))] = pk;
    }
  }
  __syncthreads();

  const int lr = l & 15;
  const int lk = l >> 4;

  f32x4 acc[2][8];
  #pragma unroll
  for (int rt = 0; rt < 2; ++rt)
    #pragma unroll
    for (int ct = 0; ct < 8; ++ct) acc[rt][ct] = (f32x4){0.f, 0.f, 0.f, 0.f};

  #pragma unroll
  for (int ks = 0; ks < 4; ++ks) {
    const int kofs = ks * 4 + lk;
    bf16x8 af[2], wf[8];
    #pragma unroll
    for (int rt = 0; rt < 2; ++rt) {
      int r = wv * 32 + rt * 16 + lr;
      af[rt] = *reinterpret_cast<const bf16x8*>(&lA[(r << 4) | (kofs ^ (r & 7))]);
    }
    #pragma unroll
    for (int ct = 0; ct < 8; ++ct) {
      int r = ct * 16 + lr;
      wf[ct] = *reinterpret_cast<const bf16x8*>(&lW[(r << 4) | (kofs ^ (r & 7))]);
    }
    #pragma unroll
    for (int rt = 0; rt < 2; ++rt)
      #pragma unroll
      for (int ct = 0; ct < 8; ++ct)
        acc[rt][ct] = __builtin_amdgcn_mfma_f32_16x16x32_bf16(af[rt], wf[ct], acc[rt][ct], 0, 0, 0);
  }

  float bb[8], rr[8], ss[8], tt[8];
  #pragma unroll
  for (int ct = 0; ct < 8; ++ct) {
    int c = ct * 16 + lr;
    bb[ct] = bl[c]; rr[ct] = rootl[c]; ss[ct] = sl[c]; tt[ct] = tl[c];
  }

  #pragma unroll
  for (int rt = 0; rt < 2; ++rt) {
    #pragma unroll
    for (int rg = 0; rg < 4; ++rg) {
      int gn = row0 + wv * 32 + rt * 16 + lk * 4 + rg;
      if (gn >= N) continue;
      float di = dinv[gn];
      float invdeg = di * di;
      #pragma unroll
      for (int ct = 0; ct < 8; ++ct) {
        int c = ct * 16 + lr;
        float o = acc[rt][ct][rg] + bb[ct];
        hl[(size_t)gn * DF + c] = f2b(o);
        float se = fmaxf(o + rr[ct], 0.f) * invdeg;
        float av2 = ss[ct] * se + tt[ct];
        if constexpr (sizeof(AT) == 4) accOut[(size_t)gn * DF + c] = av2;
        else                           accOut[(size_t)gn * DF + c] = f2b(av2);
      }
    }
  }
}

// ---------------- segmented gather-reduce ----------------
// 4 destination nodes per wave, 16 lanes/node, uint4 (8 bf16 feats) per lane.
// src/nrm prefetched 16-wide and broadcast via shfl -> no dependent chain.
// Epilogue: o = seed + s * msgsum; RELU fold for layers < last.
template <typename AT, bool RELU>
__global__ __launch_bounds__(256) void k_gather(
    const int* __restrict__ start, const int* __restrict__ indeg,
    const int* __restrict__ srcS, const float* __restrict__ nrmS,
    const uint32_t* __restrict__ epS,
    const uint4* __restrict__ hl4,
    const float* __restrict__ sl,
    AT* acc, int N)
{
  int gw = (blockIdx.x * blockDim.x + threadIdx.x) >> 6;
  int lane = threadIdx.x & 63;
  int s16 = lane & 15;
  int nd = gw * 4 + (lane >> 4);
  if (nd >= N) return;
  int base = start[nd], n = indeg[nd];
  const uint32_t sh = (s16 & 1) * 16;
  const int dw = s16 >> 1;

  float a[8];
  #pragma unroll
  for (int j = 0; j < 8; ++j) a[j] = 0.f;

  for (int c0 = 0; c0 < n; c0 += 16) {
    int m = min(16, n - c0);
    int myIdx = base + c0 + s16;
    int mySrc = (s16 < m) ? srcS[myIdx] : 0;
    float myNrm = (s16 < m) ? nrmS[myIdx] : 0.f;
    #pragma unroll 2
    for (int k = 0; k < m; ++k) {
      int src = __shfl(mySrc, k, 16);
      float nr = __shfl(myNrm, k, 16);
      uint32_t pw = epS[(size_t)(base + c0 + k) * 8 + dw];
      uint4 hw = hl4[(size_t)src * 16 + s16];
      float h, ev;
      h = b2f(hw.x & 0xffffu); ev = (float)((pw >> (sh + 0)) & 3u);  a[0] += nr * fmaxf(h + ev, 0.f);
      h = b2f(hw.x >> 16);     ev = (float)((pw >> (sh + 2)) & 3u);  a[1] += nr * fmaxf(h + ev, 0.f);
      h = b2f(hw.y & 0xffffu); ev = (float)((pw >> (sh + 4)) & 3u);  a[2] += nr * fmaxf(h + ev, 0.f);
      h = b2f(hw.y >> 16);     ev = (float)((pw >> (sh + 6)) & 3u);  a[3] += nr * fmaxf(h + ev, 0.f);
      h = b2f(hw.z & 0xffffu); ev = (float)((pw >> (sh + 8)) & 3u);  a[4] += nr * fmaxf(h + ev, 0.f);
      h = b2f(hw.z >> 16);     ev = (float)((pw >> (sh + 10)) & 3u); a[5] += nr * fmaxf(h + ev, 0.f);
      h = b2f(hw.w & 0xffffu); ev = (float)((pw >> (sh + 12)) & 3u); a[6] += nr * fmaxf(h + ev, 0.f);
      h = b2f(hw.w >> 16);     ev = (float)((pw >> (sh + 14)) & 3u); a[7] += nr * fmaxf(h + ev, 0.f);
    }
  }

  float s8[8];
  ((float4*)s8)[0] = ((const float4*)sl)[s16 * 2];
  ((float4*)s8)[1] = ((const float4*)sl)[s16 * 2 + 1];

  if constexpr (sizeof(AT) == 2) {
    uint4* ap = (uint4*)acc + (size_t)nd * 16 + s16;
    uint4 p = *ap;
    float o[8];
    o[0] = b2f(p.x & 0xffffu) + s8[0] * a[0];
    o[1] = b2f(p.x >> 16)     + s8[1] * a[1];
    o[2] = b2f(p.y & 0xffffu) + s8[2] * a[2];
    o[3] = b2f(p.y >> 16)     + s8[3] * a[3];
    o[4] = b2f(p.z & 0xffffu) + s8[4] * a[4];
    o[5] = b2f(p.z >> 16)     + s8[5] * a[5];
    o[6] = b2f(p.w & 0xffffu) + s8[6] * a[6];
    o[7] = b2f(p.w >> 16)     + s8[7] * a[7];
    if (RELU) {
      #pragma unroll
      for (int j = 0; j < 8; ++j) o[j] = fmaxf(o[j], 0.f);
    }
    p.x = pk2(o[0], o[1]); p.y = pk2(o[2], o[3]);
    p.z = pk2(o[4], o[5]); p.w = pk2(o[6], o[7]);
    *ap = p;
  } else {
    float4* ap = (float4*)acc + (size_t)nd * 32 + s16 * 2;
    float4 p0 = ap[0], p1 = ap[1];
    p0.x += s8[0] * a[0]; p0.y += s8[1] * a[1];
    p0.z += s8[2] * a[2]; p0.w += s8[3] * a[3];
    p1.x += s8[4] * a[4]; p1.y += s8[5] * a[5];
    p1.z += s8[6] * a[6]; p1.w += s8[7] * a[7];
    if (RELU) {
      p0.x = fmaxf(p0.x, 0.f); p0.y = fmaxf(p0.y, 0.f);
      p0.z = fmaxf(p0.z, 0.f); p0.w = fmaxf(p0.w, 0.f);
      p1.x = fmaxf(p1.x, 0.f); p1.y = fmaxf(p1.y, 0.f);
      p1.z = fmaxf(p1.z, 0.f); p1.w = fmaxf(p1.w, 0.f);
    }
    ap[0] = p0; ap[1] = p1;
  }
}

// ---------------- launch ----------------
extern "C" void kernel_launch(void* const* d_in, const int* in_sizes, int n_in,
                              void* d_out, int out_size, void* d_ws, size_t ws_size,
                              hipStream_t stream) {
  const float* x     = (const float*)d_in[0];
  const int*   ei    = (const int*)d_in[1];
  const int*   ea    = (const int*)d_in[2];
  const float* W     = (const float*)d_in[3];
  const float* b     = (const float*)d_in[4];
  const float* root  = (const float*)d_in[5];
  const float* gamma = (const float*)d_in[6];
  const float* beta  = (const float*)d_in[7];
  const float* mean  = (const float*)d_in[8];
  const float* var   = (const float*)d_in[9];

  const int N = in_sizes[0] / DF;
  const int E = in_sizes[1] / 2;
  const int* row = ei;
  const int* col = ei + E;

  char* ws = (char*)d_ws;
  size_t off = 0;
  auto alloc = [&](size_t bytes) -> void* {
    void* p = ws + off;
    off = (off + bytes + 255) & ~(size_t)255;
    return p;
  };
  // keep degi/indeg/counter adjacent: zeroed with ONE memset
  int*      degi   = (int*)alloc((size_t)N * 4);
  int*      indeg  = (int*)alloc((size_t)N * 4);
  int*      counter= (int*)alloc(256);
  size_t    zspan  = (size_t)((char*)ws + off - (char*)degi);
  float*    dinv   = (float*)alloc((size_t)N * 4);
  int*      startA = (int*)alloc((size_t)N * 4);
  int*      cursor = (int*)alloc((size_t)N * 4);
  int*      srcS   = (int*)alloc((size_t)E * 4);
  float*    nrmS   = (float*)alloc((size_t)E * 4);
  uint32_t* epS    = (uint32_t*)alloc((size_t)E * 8 * 4);
  float*    sbuf   = (float*)alloc((size_t)NL * DF * 4);
  float*    tbuf   = (float*)alloc((size_t)NL * DF * 4);
  ushort*   Wb     = (ushort*)alloc((size_t)NL * DF * DF * 2);
  ushort*   hl     = (ushort*)alloc((size_t)N * DF * 2);
  ushort*   accA   = (ushort*)alloc((size_t)N * DF * 2);

  hipMemsetAsync(degi, 0, zspan, stream);

  k_deg2<<<(E + 255) / 256, 256, 0, stream>>>(row, col, degi, indeg, E);
  k_dinv<<<(N + 255) / 256, 256, 0, stream>>>(degi, dinv, N);
  k_start<<<(N + 255) / 256, 256, 0, stream>>>(indeg, startA, cursor, counter, N);
  k_fillpack<<<(E * 8 + 255) / 256, 256, 0, stream>>>(row, col, dinv, cursor,
                                                      srcS, nrmS, ea, epS, E);
  k_params<<<(NL * DF * DF + 255) / 256, 256, 0, stream>>>(
      gamma, beta, mean, var, sbuf, tbuf, W, Wb, NL * DF, NL * DF * DF);

  float* outp = (float*)d_out;
  const int gemmGrid = (N + 127) / 128;
  const int gathGrid = ((N + 3) / 4 * 64 + 255) / 256;

  // layer 0: fp32 in (no relu) -> bf16 seed; gather writes relu'd h
  k_gemm<float, ushort><<<gemmGrid, 256, 0, stream>>>(
      x, Wb, b, root, sbuf, tbuf, dinv, hl, accA, N);
  k_gather<ushort, true><<<gathGrid, 256, 0, stream>>>(
      startA, indeg, srcS, nrmS, epS, (const uint4*)hl, sbuf, accA, N);

  for (int l = 1; l < NL - 1; ++l) {
    k_gemm<ushort, ushort><<<gemmGrid, 256, 0, stream>>>(
        accA, Wb + (size_t)l * DF * DF, b + (size_t)l * DF, root + (size_t)l * DF,
        sbuf + (size_t)l * DF, tbuf + (size_t)l * DF, dinv, hl, accA, N);
    k_gather<ushort, true><<<gathGrid, 256, 0, stream>>>(
        startA, indeg, srcS, nrmS, epS, (const uint4*)hl,
        sbuf + (size_t)l * DF, accA, N);
  }

  {
    const int l = NL - 1;
    k_gemm<ushort, float><<<gemmGrid, 256, 0, stream>>>(
        accA, Wb + (size_t)l * DF * DF, b + (size_t)l * DF, root + (size_t)l * DF,
        sbuf + (size_t)l * DF, tbuf + (size_t)l * DF, dinv, hl, outp, N);
    k_gather<float, false><<<gathGrid, 256, 0, stream>>>(
        startA, indeg, srcS, nrmS, epS, (const uint4*)hl,
        sbuf + (size_t)l * DF, outp, N);
  }
}